// Round 20
// baseline (94.998 us; speedup 1.0000x reference)
//
#include <hip/hip_runtime.h>
#include <hip/hip_bf16.h>

#define EPS 1e-5f

typedef _Float16 f16x8 __attribute__((ext_vector_type(8)));
typedef _Float16 f16x4 __attribute__((ext_vector_type(4)));
typedef short short8v __attribute__((ext_vector_type(8)));
typedef float f32x4 __attribute__((ext_vector_type(4)));

static __device__ __forceinline__ unsigned short f2h(float x) {
    _Float16 h = (_Float16)x;
    return *reinterpret_cast<unsigned short*>(&h);
}

// ------- Kernel 1: 1x1 convs as MFMA GEMM (unchanged from R17) -------
__global__ __launch_bounds__(512) void conv_kv_kernel(const float* __restrict__ v,
                               const float* __restrict__ k_w, const float* __restrict__ v_w,
                               const float* __restrict__ kg, const float* __restrict__ kbe,
                               const float* __restrict__ km, const float* __restrict__ kvv,
                               unsigned short* __restrict__ Kt, unsigned short* __restrict__ Vt) {
    __shared__ unsigned short vtile[32 * 136];       // [m][c] fp16, stride 136
    const int t = threadIdx.x;                       // 0..511
    const int w = t >> 6, lane = t & 63, g = lane >> 4, qr = lane & 15;
    const int wo = w >> 1, mh = w & 1;               // o-block, m-half
    const int b = blockIdx.y, m0 = blockIdx.x * 32;

    float4 vstg[2];
#pragma unroll
    for (int r = 0; r < 2; ++r) {
        int idx = r * 512 + t;
        int c = idx >> 3, mq = idx & 7;
        vstg[r] = *reinterpret_cast<const float4*>(&v[((size_t)b * 128 + c) * 1024 + m0 + mq * 4]);
    }
    float4 kwl[4][2], vwl[4][2];
#pragma unroll
    for (int ck = 0; ck < 4; ++ck) {
        const float* kp = &k_w[(16 * wo + qr) * 128 + 32 * ck + 8 * g];
        const float* vp = &v_w[(16 * wo + qr) * 128 + 32 * ck + 8 * g];
        kwl[ck][0] = *reinterpret_cast<const float4*>(kp);
        kwl[ck][1] = *reinterpret_cast<const float4*>(kp + 4);
        vwl[ck][0] = *reinterpret_cast<const float4*>(vp);
        vwl[ck][1] = *reinterpret_cast<const float4*>(vp + 4);
    }
#pragma unroll
    for (int r = 0; r < 2; ++r) {
        int idx = r * 512 + t;
        int c = idx >> 3, mq = idx & 7;
        vtile[(mq * 4 + 0) * 136 + c] = f2h(vstg[r].x);
        vtile[(mq * 4 + 1) * 136 + c] = f2h(vstg[r].y);
        vtile[(mq * 4 + 2) * 136 + c] = f2h(vstg[r].z);
        vtile[(mq * 4 + 3) * 136 + c] = f2h(vstg[r].w);
    }
    __syncthreads();

    f16x8 kwf[4], vwf[4];
#pragma unroll
    for (int ck = 0; ck < 4; ++ck)
#pragma unroll
        for (int j = 0; j < 8; ++j) {
            kwf[ck][j] = (_Float16)(j < 4 ? kwl[ck][0][j] : kwl[ck][1][j - 4]);
            vwf[ck][j] = (_Float16)(j < 4 ? vwl[ck][0][j] : vwl[ck][1][j - 4]);
        }

    f16x8 bf[4];
#pragma unroll
    for (int ck = 0; ck < 4; ++ck)
        bf[ck] = *reinterpret_cast<const f16x8*>(&vtile[(mh * 16 + qr) * 136 + 32 * ck + 8 * g]);
    f32x4 aK = {0.f, 0.f, 0.f, 0.f}, aV = {0.f, 0.f, 0.f, 0.f};
#pragma unroll
    for (int ck = 0; ck < 4; ++ck) {
        aK = __builtin_amdgcn_mfma_f32_16x16x32_f16(kwf[ck], bf[ck], aK, 0, 0, 0);
        aV = __builtin_amdgcn_mfma_f32_16x16x32_f16(vwf[ck], bf[ck], aV, 0, 0, 0);
    }

    const int m = m0 + mh * 16 + qr;
#pragma unroll
    for (int i = 0; i < 4; ++i) {
        int o = 16 * wo + 4 * g + i;
        float invk = kg[o] * rsqrtf(kvv[o] + EPS);
        float biask = kbe[o] - km[o] * invk;
        Kt[((size_t)b * 1024 + m) * 64 + o] = f2h(aK[i] * invk + biask);
        Vt[((size_t)b * 64 + o) * 1024 + m] = f2h(aV[i]);
    }
}

// ------- Kernel 2: fused BN(q) + flash attn; grid (128,8)=1024 WGs, 32 q-rows/WG;
//         4 waves = 4 KV-quarters, 2 q-bodies/wave; LDS 39936 (ib/mlb overlay)
//         -> 4 WG/CU = 4 waves/SIMD (occupancy x2 vs R15). -------
__global__ __launch_bounds__(256, 4) void attn_kernel(const float* __restrict__ q,
        const float* __restrict__ qg, const float* __restrict__ qbt,
        const float* __restrict__ qm, const float* __restrict__ qv,
        const unsigned short* __restrict__ Kt, const unsigned short* __restrict__ Vt,
        float* __restrict__ out) {
    // LDS bytes: [0,38912) 4x(K 32x72 + V 64x40) tiles (epilogue: obuf 32x68 f32 overlays)
    //            [38912,39936) union{ ib (512B, prologue) | mlb (1024B, epilogue) }
    __shared__ __align__(16) unsigned char smem[39936];
    unsigned short* S16 = (unsigned short*)smem;
    float* SF = (float*)smem;
    const int t = threadIdx.x;
    const int w = t >> 6, lane = t & 63, g = lane >> 4, qr = lane & 15;
    const int b = blockIdx.y, n0 = blockIdx.x * 32;

    unsigned short* kT = S16 + w * 4864;             // [key32][72]
    unsigned short* vT = kT + 2304;                  // [c64][40]
    float* ib  = SF + 9728;                          // prologue-only
    float* mlb = SF + 9728;                          // epilogue-only (overlay)

    const int koff0 = w * 256;                       // this wave's KV-quarter
    const int kr_row = lane >> 3, kr_sub = lane & 7;
    const int vr_row = lane >> 2, vr_sub = lane & 3;

    short8v kpf[4], vpf[4];
#pragma unroll
    for (int ch = 0; ch < 4; ++ch) {                 // tile 0 loads in flight under setup
        kpf[ch] = *reinterpret_cast<const short8v*>(
            Kt + (size_t)(b * 1024 + koff0 + ch * 8 + kr_row) * 64 + kr_sub * 8);
        vpf[ch] = *reinterpret_cast<const short8v*>(
            Vt + (size_t)(b * 64 + ch * 16 + vr_row) * 1024 + koff0 + vr_sub * 8);
    }

    if (t < 64) {
        float inv = qg[t] * rsqrtf(qv[t] + EPS);
        ib[t] = inv * 1.44269504f;                   // softmax in base-2
        ib[64 + t] = (qbt[t] - qm[t] * inv) * 1.44269504f;
    }
    __syncthreads();

    // 2 q-bodies: rows n0 + j*16 + qr
    f16x8 qf0[2], qf1[2];
#pragma unroll
    for (int j = 0; j < 2; ++j) {
        int nq = n0 + j * 16 + qr;
#pragma unroll
        for (int e = 0; e < 8; ++e) {
            int c0 = g * 8 + e, c1 = 32 + g * 8 + e;
            qf0[j][e] = (_Float16)(q[(size_t)(b * 64 + c0) * 4096 + nq] * ib[c0] + ib[64 + c0]);
            qf1[j][e] = (_Float16)(q[(size_t)(b * 64 + c1) * 4096 + nq] * ib[c1] + ib[64 + c1]);
        }
    }

#pragma unroll
    for (int ch = 0; ch < 4; ++ch) {                 // land tile 0 (wave-private, no barrier)
        *reinterpret_cast<short8v*>(kT + (ch * 8 + kr_row) * 72 + kr_sub * 8) = kpf[ch];
        *reinterpret_cast<short8v*>(vT + (ch * 16 + vr_row) * 40 + vr_sub * 8) = vpf[ch];
    }

    f32x4 oacc[2][4];                                // [body][cb]
#pragma unroll
    for (int j = 0; j < 2; ++j)
#pragma unroll
        for (int cb = 0; cb < 4; ++cb) oacc[j][cb] = (f32x4){0, 0, 0, 0};
    float mr[2] = {-1e30f, -1e30f};
    float lp[2] = {0.f, 0.f};

#pragma unroll 1
    for (int i = 0; i < 8; ++i) {
        f16x8 kfA0 = *reinterpret_cast<const f16x8*>(kT + qr * 72 + g * 8);
        f16x8 kfA1 = *reinterpret_cast<const f16x8*>(kT + qr * 72 + 32 + g * 8);
        f16x8 kfB0 = *reinterpret_cast<const f16x8*>(kT + (16 + qr) * 72 + g * 8);
        f16x8 kfB1 = *reinterpret_cast<const f16x8*>(kT + (16 + qr) * 72 + 32 + g * 8);
        f16x4 vfA[4], vfB[4];
#pragma unroll
        for (int cb = 0; cb < 4; ++cb) {
            vfA[cb] = *reinterpret_cast<const f16x4*>(vT + (cb * 16 + qr) * 40 + g * 4);
            vfB[cb] = *reinterpret_cast<const f16x4*>(vT + (cb * 16 + qr) * 40 + 16 + g * 4);
        }
        if (i < 7) {                                 // T14: next tile loads issued now
            int ko = koff0 + (i + 1) * 32;
#pragma unroll
            for (int ch = 0; ch < 4; ++ch) {
                kpf[ch] = *reinterpret_cast<const short8v*>(
                    Kt + (size_t)(b * 1024 + ko + ch * 8 + kr_row) * 64 + kr_sub * 8);
                vpf[ch] = *reinterpret_cast<const short8v*>(
                    Vt + (size_t)(b * 64 + ch * 16 + vr_row) * 1024 + ko + vr_sub * 8);
            }
        }
#pragma unroll
        for (int j = 0; j < 2; ++j) {
            f32x4 s0, s1;
            {
                f32x4 a = {0, 0, 0, 0};
                a  = __builtin_amdgcn_mfma_f32_16x16x32_f16(kfA0, qf0[j], a, 0, 0, 0);
                s0 = __builtin_amdgcn_mfma_f32_16x16x32_f16(kfA1, qf1[j], a, 0, 0, 0);
            }
            {
                f32x4 a = {0, 0, 0, 0};
                a  = __builtin_amdgcn_mfma_f32_16x16x32_f16(kfB0, qf0[j], a, 0, 0, 0);
                s1 = __builtin_amdgcn_mfma_f32_16x16x32_f16(kfB1, qf1[j], a, 0, 0, 0);
            }
            float lmax = fmaxf(fmaxf(fmaxf(s0[0], s0[1]), fmaxf(s0[2], s0[3])),
                               fmaxf(fmaxf(s1[0], s1[1]), fmaxf(s1[2], s1[3])));
            if (!__all(lmax - mr[j] <= 11.0f)) {
                float tm = fmaxf(lmax, __shfl_xor(lmax, 16));
                tm = fmaxf(tm, __shfl_xor(tm, 32));
                float mn = fmaxf(mr[j], tm);
                float sc = exp2f(mr[j] - mn);
                lp[j] *= sc;
                oacc[j][0] *= sc; oacc[j][1] *= sc; oacc[j][2] *= sc; oacc[j][3] *= sc;
                mr[j] = mn;
            }
            float p0 = exp2f(s0[0] - mr[j]), p1 = exp2f(s0[1] - mr[j]);
            float p2 = exp2f(s0[2] - mr[j]), p3 = exp2f(s0[3] - mr[j]);
            float p4 = exp2f(s1[0] - mr[j]), p5 = exp2f(s1[1] - mr[j]);
            float p6 = exp2f(s1[2] - mr[j]), p7 = exp2f(s1[3] - mr[j]);
            lp[j] += ((p0 + p1) + (p2 + p3)) + ((p4 + p5) + (p6 + p7));
            uint2 u0, u1;
            u0.x = __builtin_bit_cast(unsigned int, __builtin_amdgcn_cvt_pkrtz(p0, p1));
            u0.y = __builtin_bit_cast(unsigned int, __builtin_amdgcn_cvt_pkrtz(p2, p3));
            u1.x = __builtin_bit_cast(unsigned int, __builtin_amdgcn_cvt_pkrtz(p4, p5));
            u1.y = __builtin_bit_cast(unsigned int, __builtin_amdgcn_cvt_pkrtz(p6, p7));
            f16x4 pf0 = __builtin_bit_cast(f16x4, u0);
            f16x4 pf1 = __builtin_bit_cast(f16x4, u1);
#pragma unroll
            for (int cb = 0; cb < 4; ++cb) {
                oacc[j][cb] = __builtin_amdgcn_mfma_f32_16x16x16f16(vfA[cb], pf0, oacc[j][cb], 0, 0, 0);
                oacc[j][cb] = __builtin_amdgcn_mfma_f32_16x16x16f16(vfB[cb], pf1, oacc[j][cb], 0, 0, 0);
            }
        }
        if (i < 7) {                                 // land tile i+1 (wave-private overwrite)
#pragma unroll
            for (int ch = 0; ch < 4; ++ch) {
                *reinterpret_cast<short8v*>(kT + (ch * 8 + kr_row) * 72 + kr_sub * 8) = kpf[ch];
                *reinterpret_cast<short8v*>(vT + (ch * 16 + vr_row) * 40 + vr_sub * 8) = vpf[ch];
            }
        }
    }

    float lred[2];
#pragma unroll
    for (int j = 0; j < 2; ++j) {
        float l = lp[j] + __shfl_xor(lp[j], 16);
        lred[j] = l + __shfl_xor(l, 32);
    }
    __syncthreads();                                 // ib dead; mlb takes the region
    if (g == 0) {
#pragma unroll
        for (int j = 0; j < 2; ++j) {
            mlb[((w * 2 + j) * 16 + qr) * 2] = mr[j];
            mlb[((w * 2 + j) * 16 + qr) * 2 + 1] = lred[j];
        }
    }
    __syncthreads();
    // per body j: combine 4 quarters' (m,l); scale own partial by exp2(m_w - M)/L
#pragma unroll
    for (int j = 0; j < 2; ++j) {
        float m0 = mlb[((0 * 2 + j) * 16 + qr) * 2], l0 = mlb[((0 * 2 + j) * 16 + qr) * 2 + 1];
        float m1 = mlb[((1 * 2 + j) * 16 + qr) * 2], l1 = mlb[((1 * 2 + j) * 16 + qr) * 2 + 1];
        float m2 = mlb[((2 * 2 + j) * 16 + qr) * 2], l2 = mlb[((2 * 2 + j) * 16 + qr) * 2 + 1];
        float m3 = mlb[((3 * 2 + j) * 16 + qr) * 2], l3 = mlb[((3 * 2 + j) * 16 + qr) * 2 + 1];
        float M = fmaxf(fmaxf(m0, m1), fmaxf(m2, m3));
        float e0 = exp2f(m0 - M), e1 = exp2f(m1 - M), e2 = exp2f(m2 - M), e3 = exp2f(m3 - M);
        float L = e0 * l0 + e1 * l1 + e2 * l2 + e3 * l3;
        float ew = (w == 0) ? e0 : (w == 1) ? e1 : (w == 2) ? e2 : e3;
        float sc = ew / L;
#pragma unroll
        for (int cb = 0; cb < 4; ++cb) oacc[j][cb] *= sc;
    }
    // accumulate the 4 quarters into obuf (overlays dead tiles), 4 barrier rounds
    float* ob = SF;                                   // [row32][68]
#pragma unroll 1
    for (int r = 0; r < 4; ++r) {
        if (w == r) {
#pragma unroll
            for (int j = 0; j < 2; ++j)
#pragma unroll
                for (int cb = 0; cb < 4; ++cb) {
                    float* dp = &ob[(j * 16 + qr) * 68 + cb * 16 + g * 4];
                    if (r == 0) *reinterpret_cast<f32x4*>(dp) = oacc[j][cb];
                    else {
                        f32x4 cur = *reinterpret_cast<const f32x4*>(dp);
                        *reinterpret_cast<f32x4*>(dp) = cur + oacc[j][cb];
                    }
                }
        }
        __syncthreads();
    }
    // write out: thread covers row = t&31, channels (t>>5)*8 .. +7
    const int row = t & 31, cg = t >> 5;
#pragma unroll
    for (int k = 0; k < 2; ++k) {
        f32x4 val = *reinterpret_cast<const f32x4*>(&ob[row * 68 + cg * 8 + k * 4]);
#pragma unroll
        for (int e = 0; e < 4; ++e) {
            int c = cg * 8 + k * 4 + e;
            out[(size_t)(b * 64 + c) * 4096 + n0 + row] = val[e];
        }
    }
}

extern "C" void kernel_launch(void* const* d_in, const int* in_sizes, int n_in,
                              void* d_out, int out_size, void* d_ws, size_t ws_size,
                              hipStream_t stream) {
    const float* q   = (const float*)d_in[0];
    const float* v   = (const float*)d_in[1];
    const float* k_w = (const float*)d_in[2];
    const float* v_w = (const float*)d_in[3];
    const float* qg  = (const float*)d_in[4];
    const float* qb  = (const float*)d_in[5];
    const float* qm  = (const float*)d_in[6];
    const float* qv  = (const float*)d_in[7];
    const float* kg  = (const float*)d_in[8];
    const float* kbe = (const float*)d_in[9];
    const float* km  = (const float*)d_in[10];
    const float* kvv = (const float*)d_in[11];

    unsigned short* Kt = (unsigned short*)d_ws;            // 8*1024*64 fp16 = 1 MB
    unsigned short* Vt = Kt + (size_t)8 * 1024 * 64;       // 1 MB

    conv_kv_kernel<<<dim3(32, 8), 512, 0, stream>>>(v, k_w, v_w, kg, kbe, km, kvv, Kt, Vt);
    attn_kernel<<<dim3(128, 8), 256, 0, stream>>>(q, qg, qb, qm, qv, Kt, Vt, (float*)d_out);
}

// Round 22
// 33.623 us; speedup vs baseline: 2.8254x; 2.8254x over previous
//
#include <hip/hip_runtime.h>
#include <hip/hip_bf16.h>

#define EPS 1e-5f

typedef _Float16 f16x8 __attribute__((ext_vector_type(8)));
typedef _Float16 f16x4 __attribute__((ext_vector_type(4)));
typedef short short8v __attribute__((ext_vector_type(8)));
typedef float f32x4 __attribute__((ext_vector_type(4)));

static __device__ __forceinline__ unsigned short f2h(float x) {
    _Float16 h = (_Float16)x;
    return *reinterpret_cast<unsigned short*>(&h);
}

// guaranteed single v_exp_f32 (2^x); pure VALU asm, value-dep only
static __device__ __forceinline__ float fexp2(float x) {
    float r;
    asm("v_exp_f32 %0, %1" : "=v"(r) : "v"(x));
    return r;
}

// ------- Kernel 1: 1x1 convs as MFMA GEMM: K (B,Nv,64) fp16, V^T (B,64,Nv) fp16 -------
__global__ __launch_bounds__(256) void conv_kv_kernel(const float* __restrict__ v,
                               const float* __restrict__ k_w, const float* __restrict__ v_w,
                               const float* __restrict__ kg, const float* __restrict__ kbe,
                               const float* __restrict__ km, const float* __restrict__ kvv,
                               unsigned short* __restrict__ Kt, unsigned short* __restrict__ Vt) {
    __shared__ unsigned short vtile[32 * 136];
    const int t = threadIdx.x;
    const int w = t >> 6, lane = t & 63, g = lane >> 4, qr = lane & 15;
    const int b = blockIdx.y, m0 = blockIdx.x * 32;

    float4 vstg[4];
#pragma unroll
    for (int r = 0; r < 4; ++r) {
        int idx = r * 256 + t;
        int c = idx >> 3, mq = idx & 7;
        vstg[r] = *reinterpret_cast<const float4*>(&v[((size_t)b * 128 + c) * 1024 + m0 + mq * 4]);
    }
    float4 kwl[4][2], vwl[4][2];
#pragma unroll
    for (int ck = 0; ck < 4; ++ck) {
        const float* kp = &k_w[(16 * w + qr) * 128 + 32 * ck + 8 * g];
        const float* vp = &v_w[(16 * w + qr) * 128 + 32 * ck + 8 * g];
        kwl[ck][0] = *reinterpret_cast<const float4*>(kp);
        kwl[ck][1] = *reinterpret_cast<const float4*>(kp + 4);
        vwl[ck][0] = *reinterpret_cast<const float4*>(vp);
        vwl[ck][1] = *reinterpret_cast<const float4*>(vp + 4);
    }
#pragma unroll
    for (int r = 0; r < 4; ++r) {
        int idx = r * 256 + t;
        int c = idx >> 3, mq = idx & 7;
        vtile[(mq * 4 + 0) * 136 + c] = f2h(vstg[r].x);
        vtile[(mq * 4 + 1) * 136 + c] = f2h(vstg[r].y);
        vtile[(mq * 4 + 2) * 136 + c] = f2h(vstg[r].z);
        vtile[(mq * 4 + 3) * 136 + c] = f2h(vstg[r].w);
    }
    __syncthreads();

    f16x8 kwf[4], vwf[4];
#pragma unroll
    for (int ck = 0; ck < 4; ++ck)
#pragma unroll
        for (int j = 0; j < 8; ++j) {
            kwf[ck][j] = (_Float16)(j < 4 ? kwl[ck][0][j] : kwl[ck][1][j - 4]);
            vwf[ck][j] = (_Float16)(j < 4 ? vwl[ck][0][j] : vwl[ck][1][j - 4]);
        }

    f32x4 accK[2], accV[2];
#pragma unroll
    for (int mb = 0; mb < 2; ++mb) {
        f16x8 bf[4];
#pragma unroll
        for (int ck = 0; ck < 4; ++ck)
            bf[ck] = *reinterpret_cast<const f16x8*>(&vtile[(mb * 16 + qr) * 136 + 32 * ck + 8 * g]);
        f32x4 aK = {0.f, 0.f, 0.f, 0.f}, aV = {0.f, 0.f, 0.f, 0.f};
#pragma unroll
        for (int ck = 0; ck < 4; ++ck) {
            aK = __builtin_amdgcn_mfma_f32_16x16x32_f16(kwf[ck], bf[ck], aK, 0, 0, 0);
            aV = __builtin_amdgcn_mfma_f32_16x16x32_f16(vwf[ck], bf[ck], aV, 0, 0, 0);
        }
        accK[mb] = aK; accV[mb] = aV;
    }

    float invk_i[4], biask_i[4];
#pragma unroll
    for (int i = 0; i < 4; ++i) {
        int o = 16 * w + 4 * g + i;
        invk_i[i] = kg[o] * rsqrtf(kvv[o] + EPS);
        biask_i[i] = kbe[o] - km[o] * invk_i[i];
    }
#pragma unroll
    for (int mb = 0; mb < 2; ++mb) {
        int m = m0 + mb * 16 + qr;
#pragma unroll
        for (int i = 0; i < 4; ++i) {
            int o = 16 * w + 4 * g + i;
            Kt[((size_t)b * 1024 + m) * 64 + o] = f2h(accK[mb][i] * invk_i[i] + biask_i[i]);
            Vt[((size_t)b * 64 + o) * 1024 + m] = f2h(accV[mb][i]);
        }
    }
}

// ------- Kernel 2: fused BN(q) + flash attn; grid (64,8), 4 waves = 4 KV-quarters,
//         4 q-bodies/wave; P fed directly to PV via mfma 16x16x16 (register path);
//         4-way in-LDS merge. (R15 structure — best measured 38.3 µs) -------
__global__ __launch_bounds__(256, 2) void attn_kernel(const float* __restrict__ q,
        const float* __restrict__ qg, const float* __restrict__ qbt,
        const float* __restrict__ qm, const float* __restrict__ qv,
        const unsigned short* __restrict__ Kt, const unsigned short* __restrict__ Vt,
        float* __restrict__ out) {
    // LDS bytes: [0,38912) 4x(K 32x72 + V 64x40) tiles (epilogue: obuf 64x68 f32 overlays)
    //            [38912,39424) ib; [39424,41472) mlb (4w x 4j x 16qr x {m,l})
    __shared__ __align__(16) unsigned char smem[41472];
    unsigned short* S16 = (unsigned short*)smem;
    float* SF = (float*)smem;
    const int t = threadIdx.x;
    const int w = t >> 6, lane = t & 63, g = lane >> 4, qr = lane & 15;
    const int b = blockIdx.y, n0 = blockIdx.x * 64;

    unsigned short* kT = S16 + w * 4864;             // [key32][72]
    unsigned short* vT = kT + 2304;                  // [c64][40]
    float* ib  = SF + 9728;
    float* mlb = SF + 9856;                          // [w][j][qr] x {m,l}

    const int koff0 = w * 256;                       // this wave's KV-quarter
    const int kr_row = lane >> 3, kr_sub = lane & 7;
    const int vr_row = lane >> 2, vr_sub = lane & 3;

    short8v kpf[4], vpf[4];
#pragma unroll
    for (int ch = 0; ch < 4; ++ch) {                 // tile 0 loads in flight under setup
        kpf[ch] = *reinterpret_cast<const short8v*>(
            Kt + (size_t)(b * 1024 + koff0 + ch * 8 + kr_row) * 64 + kr_sub * 8);
        vpf[ch] = *reinterpret_cast<const short8v*>(
            Vt + (size_t)(b * 64 + ch * 16 + vr_row) * 1024 + koff0 + vr_sub * 8);
    }

    if (t < 64) {
        float inv = qg[t] * rsqrtf(qv[t] + EPS);
        ib[t] = inv * 1.44269504f;                   // softmax in base-2
        ib[64 + t] = (qbt[t] - qm[t] * inv) * 1.44269504f;
    }
    __syncthreads();

    // 4 q-bodies: rows n0 + j*16 + qr
    f16x8 qf0[4], qf1[4];
#pragma unroll
    for (int j = 0; j < 4; ++j) {
        int nq = n0 + j * 16 + qr;
#pragma unroll
        for (int e = 0; e < 8; ++e) {
            int c0 = g * 8 + e, c1 = 32 + g * 8 + e;
            qf0[j][e] = (_Float16)(q[(size_t)(b * 64 + c0) * 4096 + nq] * ib[c0] + ib[64 + c0]);
            qf1[j][e] = (_Float16)(q[(size_t)(b * 64 + c1) * 4096 + nq] * ib[c1] + ib[64 + c1]);
        }
    }

#pragma unroll
    for (int ch = 0; ch < 4; ++ch) {                 // land tile 0 (wave-private, no barrier)
        *reinterpret_cast<short8v*>(kT + (ch * 8 + kr_row) * 72 + kr_sub * 8) = kpf[ch];
        *reinterpret_cast<short8v*>(vT + (ch * 16 + vr_row) * 40 + vr_sub * 8) = vpf[ch];
    }

    f32x4 oacc[4][4];                                // [body][cb]
#pragma unroll
    for (int j = 0; j < 4; ++j)
#pragma unroll
        for (int cb = 0; cb < 4; ++cb) oacc[j][cb] = (f32x4){0, 0, 0, 0};
    float mr[4] = {-1e30f, -1e30f, -1e30f, -1e30f};
    float lp[4] = {0.f, 0.f, 0.f, 0.f};

#pragma unroll 1
    for (int i = 0; i < 8; ++i) {
        // --- read the whole tile i into registers (shared across all 4 bodies) ---
        f16x8 kfA0 = *reinterpret_cast<const f16x8*>(kT + qr * 72 + g * 8);
        f16x8 kfA1 = *reinterpret_cast<const f16x8*>(kT + qr * 72 + 32 + g * 8);
        f16x8 kfB0 = *reinterpret_cast<const f16x8*>(kT + (16 + qr) * 72 + g * 8);
        f16x8 kfB1 = *reinterpret_cast<const f16x8*>(kT + (16 + qr) * 72 + 32 + g * 8);
        f16x4 vfA[4], vfB[4];                        // [cb] keys blk0 (0-15), blk1 (16-31)
#pragma unroll
        for (int cb = 0; cb < 4; ++cb) {
            vfA[cb] = *reinterpret_cast<const f16x4*>(vT + (cb * 16 + qr) * 40 + g * 4);
            vfB[cb] = *reinterpret_cast<const f16x4*>(vT + (cb * 16 + qr) * 40 + 16 + g * 4);
        }
        if (i < 7) {                                 // T14: next tile loads issued now
            int ko = koff0 + (i + 1) * 32;
#pragma unroll
            for (int ch = 0; ch < 4; ++ch) {
                kpf[ch] = *reinterpret_cast<const short8v*>(
                    Kt + (size_t)(b * 1024 + ko + ch * 8 + kr_row) * 64 + kr_sub * 8);
                vpf[ch] = *reinterpret_cast<const short8v*>(
                    Vt + (size_t)(b * 64 + ch * 16 + vr_row) * 1024 + ko + vr_sub * 8);
            }
        }
        // --- 4 bodies, pure register dataflow ---
#pragma unroll
        for (int j = 0; j < 4; ++j) {
            f32x4 s0, s1;
            {
                f32x4 a = {0, 0, 0, 0};
                a  = __builtin_amdgcn_mfma_f32_16x16x32_f16(kfA0, qf0[j], a, 0, 0, 0);
                s0 = __builtin_amdgcn_mfma_f32_16x16x32_f16(kfA1, qf1[j], a, 0, 0, 0);
            }
            {
                f32x4 a = {0, 0, 0, 0};
                a  = __builtin_amdgcn_mfma_f32_16x16x32_f16(kfB0, qf0[j], a, 0, 0, 0);
                s1 = __builtin_amdgcn_mfma_f32_16x16x32_f16(kfB1, qf1[j], a, 0, 0, 0);
            }
            float lmax = fmaxf(fmaxf(fmaxf(s0[0], s0[1]), fmaxf(s0[2], s0[3])),
                               fmaxf(fmaxf(s1[0], s1[1]), fmaxf(s1[2], s1[3])));
            if (!__all(lmax - mr[j] <= 11.0f)) {
                float tm = fmaxf(lmax, __shfl_xor(lmax, 16));
                tm = fmaxf(tm, __shfl_xor(tm, 32));
                float mn = fmaxf(mr[j], tm);
                float sc = fexp2(mr[j] - mn);
                lp[j] *= sc;
                oacc[j][0] *= sc; oacc[j][1] *= sc; oacc[j][2] *= sc; oacc[j][3] *= sc;
                mr[j] = mn;
            }
            float p0 = fexp2(s0[0] - mr[j]), p1 = fexp2(s0[1] - mr[j]);
            float p2 = fexp2(s0[2] - mr[j]), p3 = fexp2(s0[3] - mr[j]);
            float p4 = fexp2(s1[0] - mr[j]), p5 = fexp2(s1[1] - mr[j]);
            float p6 = fexp2(s1[2] - mr[j]), p7 = fexp2(s1[3] - mr[j]);
            lp[j] += ((p0 + p1) + (p2 + p3)) + ((p4 + p5) + (p6 + p7));
            // P^T B-frags for mfma 16x16x16: lane(g,qr) holds k=4g..4g+3, col=qr — exactly s0/s1
            uint2 u0, u1;
            u0.x = __builtin_bit_cast(unsigned int, __builtin_amdgcn_cvt_pkrtz(p0, p1));
            u0.y = __builtin_bit_cast(unsigned int, __builtin_amdgcn_cvt_pkrtz(p2, p3));
            u1.x = __builtin_bit_cast(unsigned int, __builtin_amdgcn_cvt_pkrtz(p4, p5));
            u1.y = __builtin_bit_cast(unsigned int, __builtin_amdgcn_cvt_pkrtz(p6, p7));
            f16x4 pf0 = __builtin_bit_cast(f16x4, u0);
            f16x4 pf1 = __builtin_bit_cast(f16x4, u1);
#pragma unroll
            for (int cb = 0; cb < 4; ++cb) {
                oacc[j][cb] = __builtin_amdgcn_mfma_f32_16x16x16f16(vfA[cb], pf0, oacc[j][cb], 0, 0, 0);
                oacc[j][cb] = __builtin_amdgcn_mfma_f32_16x16x16f16(vfB[cb], pf1, oacc[j][cb], 0, 0, 0);
            }
        }
        if (i < 7) {                                 // land tile i+1 (wave-private overwrite)
#pragma unroll
            for (int ch = 0; ch < 4; ++ch) {
                *reinterpret_cast<short8v*>(kT + (ch * 8 + kr_row) * 72 + kr_sub * 8) = kpf[ch];
                *reinterpret_cast<short8v*>(vT + (ch * 16 + vr_row) * 40 + vr_sub * 8) = vpf[ch];
            }
        }
    }

    float lred[4];
#pragma unroll
    for (int j = 0; j < 4; ++j) {
        float l = lp[j] + __shfl_xor(lp[j], 16);
        lred[j] = l + __shfl_xor(l, 32);
    }
    __syncthreads();
    if (g == 0) {
#pragma unroll
        for (int j = 0; j < 4; ++j) {
            mlb[((w * 4 + j) * 16 + qr) * 2] = mr[j];
            mlb[((w * 4 + j) * 16 + qr) * 2 + 1] = lred[j];
        }
    }
    __syncthreads();
    // per body j: combine 4 quarters' (m,l); scale own partial by exp2(m_w - M)/L
#pragma unroll
    for (int j = 0; j < 4; ++j) {
        float m0 = mlb[((0 * 4 + j) * 16 + qr) * 2], l0 = mlb[((0 * 4 + j) * 16 + qr) * 2 + 1];
        float m1 = mlb[((1 * 4 + j) * 16 + qr) * 2], l1 = mlb[((1 * 4 + j) * 16 + qr) * 2 + 1];
        float m2 = mlb[((2 * 4 + j) * 16 + qr) * 2], l2 = mlb[((2 * 4 + j) * 16 + qr) * 2 + 1];
        float m3 = mlb[((3 * 4 + j) * 16 + qr) * 2], l3 = mlb[((3 * 4 + j) * 16 + qr) * 2 + 1];
        float M = fmaxf(fmaxf(m0, m1), fmaxf(m2, m3));
        float e0 = fexp2(m0 - M), e1 = fexp2(m1 - M), e2 = fexp2(m2 - M), e3 = fexp2(m3 - M);
        float L = e0 * l0 + e1 * l1 + e2 * l2 + e3 * l3;
        float ew = (w == 0) ? e0 : (w == 1) ? e1 : (w == 2) ? e2 : e3;
        float sc = ew / L;
#pragma unroll
        for (int cb = 0; cb < 4; ++cb) oacc[j][cb] *= sc;
    }
    // accumulate the 4 quarters into obuf (overlays dead tiles), 4 barrier rounds
    float* ob = SF;                                   // [row64][68]
#pragma unroll 1
    for (int r = 0; r < 4; ++r) {
        if (w == r) {
#pragma unroll
            for (int j = 0; j < 4; ++j)
#pragma unroll
                for (int cb = 0; cb < 4; ++cb) {
                    float* dp = &ob[(j * 16 + qr) * 68 + cb * 16 + g * 4];
                    if (r == 0) *reinterpret_cast<f32x4*>(dp) = oacc[j][cb];
                    else {
                        f32x4 cur = *reinterpret_cast<const f32x4*>(dp);
                        *reinterpret_cast<f32x4*>(dp) = cur + oacc[j][cb];
                    }
                }
        }
        __syncthreads();
    }
    // write out: wave w covers channels w*16..w*16+15; lane covers row=lane
    const int row = lane;
#pragma unroll
    for (int k = 0; k < 4; ++k) {
        f32x4 val = *reinterpret_cast<const f32x4*>(&ob[row * 68 + w * 16 + k * 4]);
#pragma unroll
        for (int e = 0; e < 4; ++e) {
            int c = w * 16 + k * 4 + e;
            out[(size_t)(b * 64 + c) * 4096 + n0 + row] = val[e];
        }
    }
}

extern "C" void kernel_launch(void* const* d_in, const int* in_sizes, int n_in,
                              void* d_out, int out_size, void* d_ws, size_t ws_size,
                              hipStream_t stream) {
    const float* q   = (const float*)d_in[0];
    const float* v   = (const float*)d_in[1];
    const float* k_w = (const float*)d_in[2];
    const float* v_w = (const float*)d_in[3];
    const float* qg  = (const float*)d_in[4];
    const float* qb  = (const float*)d_in[5];
    const float* qm  = (const float*)d_in[6];
    const float* qv  = (const float*)d_in[7];
    const float* kg  = (const float*)d_in[8];
    const float* kbe = (const float*)d_in[9];
    const float* km  = (const float*)d_in[10];
    const float* kvv = (const float*)d_in[11];

    unsigned short* Kt = (unsigned short*)d_ws;            // 8*1024*64 fp16 = 1 MB
    unsigned short* Vt = Kt + (size_t)8 * 1024 * 64;       // 1 MB

    conv_kv_kernel<<<dim3(32, 8), 256, 0, stream>>>(v, k_w, v_w, kg, kbe, km, kvv, Kt, Vt);
    attn_kernel<<<dim3(64, 8), 256, 0, stream>>>(q, qg, qb, qm, qv, Kt, Vt, (float*)d_out);
}